// Round 4
// baseline (381.834 us; speedup 1.0000x reference)
//
#include <hip/hip_runtime.h>
#include <hip/hip_bf16.h>

typedef __bf16 bf16;
typedef __bf16 bf16x4 __attribute__((ext_vector_type(4)));
typedef __bf16 bf16x8 __attribute__((ext_vector_type(8)));
typedef float  f32x4  __attribute__((ext_vector_type(4)));

#define MFMA16(A,B,C) __builtin_amdgcn_mfma_f32_16x16x32_bf16((A),(B),(C),0,0,0)

constexpr int NI    = 64;     // instances
constexpr int NN    = 128;    // N (output cols)
constexpr int E     = 256;    // embed dim
constexpr int HID   = 1024;   // hidden
constexpr int BATCH = 2048;
constexpr int BM    = 256;    // batch rows per block (64 per wave)
constexpr int BH    = 64;     // hidden chunk
constexpr int NCH   = HID / BH;  // 16 chunks
constexpr int HP    = BH + 8; // sH padded row

__device__ __forceinline__ float fast_gelu(float x) {
    float p = 1.5957691216f * __builtin_fmaf(0.044715f * x * x, x, x);
    return x * __builtin_amdgcn_rcpf(1.0f + __expf(-p));
}

__device__ __forceinline__ void load_lds16(const void* gp, void* lp) {
    __builtin_amdgcn_global_load_lds(
        (const __attribute__((address_space(1))) unsigned int*)gp,
        (__attribute__((address_space(3))) unsigned int*)lp, 16, 0, 0);
}

// ---------------------------------------------------------------------------
// Prepass: in [NI][R][C] f32  ->  out [NI][C][R] bf16, with 16B units within
// each out row XOR-swizzled: phys_unit = logical_unit ^ (c & 7). Tile 64Rx128C.
// Coalesced fp32 reads; full-64B-line bf16 writes.
// ---------------------------------------------------------------------------
__global__ __launch_bounds__(256) void prep_t(
    const float* __restrict__ in, bf16* __restrict__ out, int R, int C)
{
    __shared__ float t[64][132];
    const int inst = blockIdx.z;
    const int r0 = blockIdx.x * 64;      // R-dim tile base (64 rows = 8 units)
    const int c0 = blockIdx.y * 128;     // C-dim tile base
    const int tid = threadIdx.x;

    const float* ip = in + ((size_t)inst * R + r0) * C + c0;
    const int tr = tid >> 5, tc4 = tid & 31;
    #pragma unroll
    for (int i = 0; i < 8; ++i) {
        const int r = i * 8 + tr;
        *(f32x4*)&t[r][tc4 * 4] = *(const f32x4*)(ip + (size_t)r * C + tc4 * 4);
    }
    __syncthreads();

    const int c  = c0 + (tid >> 1);      // global out-row
    const int pg = (tid & 1) * 4;        // phys unit group within the 8-unit slab
    bf16* ob = out + (size_t)(inst * (size_t)C + c) * R + (size_t)(r0 + pg * 8);
    #pragma unroll
    for (int k = 0; k < 4; ++k) {
        const int p = pg + k;            // phys unit slot (0..7 in slab)
        const int u = p ^ (c & 7);       // logical unit
        bf16x8 w;
        #pragma unroll
        for (int j = 0; j < 8; ++j) w[j] = (bf16)t[u * 8 + j][tid >> 1];
        *(bf16x8*)(ob + k * 8) = w;
    }
}

// ---------------------------------------------------------------------------
// Fused MLP. PRET: W1T img [NI][HID][E], W2T img [NI][NN][HID] (bf16, swizzled)
// staged via global_load_lds, double-buffered, 1 barrier/chunk.
// Block: 256 thr = 4 waves x 64 rows; one (instance, 256-row tile); 16 chunks.
// ---------------------------------------------------------------------------
template <bool PRET>
__global__ __launch_bounds__(256, 1) void mlp3_fused(
    const int*   __restrict__ a,
    const float* __restrict__ embL,
    const float* __restrict__ embR,
    const void*  __restrict__ W1v,
    const void*  __restrict__ W2v,
    float* __restrict__ out)
{
    __shared__ __align__(16) bf16 sW1[2][BH][E];   // swizzled image, 2x32KB
    __shared__ __align__(16) bf16 sW2[2][NN][BH];  // swizzled image, 2x16KB
    __shared__ __align__(16) bf16 sH[BM][HP];      // 36.9KB  (total 133KB)

    const int blk   = blockIdx.x;                  // 512 blocks
    const int xcd   = blk & 7;
    const int j     = blk >> 3;                    // 0..63
    const int inst  = xcd + 8 * (j >> 3);          // 8 consecutive-per-XCD share inst
    const int btile = j & 7;

    const int tid  = threadIdx.x;
    const int wave = tid >> 6;
    const int lane = tid & 63;
    const int m = lane & 15;
    const int q = lane >> 4;

    const bf16* W1T = (const bf16*)W1v;
    const bf16* W2T = (const bf16*)W2v;

    // ---- DMA issue for chunk c into buf b (PRET only) ----
    auto issue_dma = [&](int c, int b) {
        // sW1: 32KB contiguous slab; 8 instrs/wave of 1KB
        const char* g1 = (const char*)(W1T + ((size_t)inst * HID + c * BH) * E);
        char* l1 = (char*)&sW1[b][0][0];
        #pragma unroll
        for (int i = 0; i < 8; ++i) {
            const int off = (wave * 8 + i) * 1024;
            load_lds16(g1 + off + lane * 16, l1 + off);
        }
        // sW2: 16KB; 4 instrs/wave; lane covers (n = 8k + lane/8, unit = lane%8)
        char* l2 = (char*)&sW2[b][0][0];
        #pragma unroll
        for (int i = 0; i < 4; ++i) {
            const int k = wave * 4 + i;
            const int n = k * 8 + (lane >> 3);
            const char* g2 = (const char*)(W2T + ((size_t)inst * NN + n) * HID)
                             + c * 128 + (lane & 7) * 16;
            load_lds16(g2, l2 + k * 1024);
        }
    };

    if (PRET) issue_dma(0, 0);

    // ---- A fragments: 64 rows x 256 e per wave, in registers ----
    bf16x8 aF[4][8];
    #pragma unroll
    for (int rt = 0; rt < 4; ++rt) {
        const int r = btile * BM + wave * 64 + rt * 16 + m;
        const int2 av = *(const int2*)(a + 2 * r);
        const float* pl = embL + ((size_t)inst * 128 + av.x) * E;
        const float* pr = embR + ((size_t)inst * 128 + av.y) * E;
        #pragma unroll
        for (int ks = 0; ks < 8; ++ks) {
            const int e0 = ks * 32 + q * 8;
            f32x4 l0 = *(const f32x4*)(pl + e0);
            f32x4 l1 = *(const f32x4*)(pl + e0 + 4);
            f32x4 r0 = *(const f32x4*)(pr + e0);
            f32x4 r1 = *(const f32x4*)(pr + e0 + 4);
            bf16x8 s;
            #pragma unroll
            for (int k = 0; k < 4; ++k) {
                s[k]     = (bf16)(l0[k] + r0[k]);
                s[k + 4] = (bf16)(l1[k] + r1[k]);
            }
            aF[rt][ks] = s;
        }
    }

    f32x4 O[4][8];
    #pragma unroll
    for (int rt = 0; rt < 4; ++rt)
        #pragma unroll
        for (int ct = 0; ct < 8; ++ct)
            O[rt][ct] = (f32x4){0.f, 0.f, 0.f, 0.f};

    #pragma unroll 1
    for (int c = 0; c < NCH; ++c) {
        const int buf = c & 1;

        if (!PRET) {
            __syncthreads();
            // VALU staging from native fp32 layouts (fallback), swizzled writes
            const float* W1f = (const float*)W1v;  // [NI][E][HID]
            const float* W2f = (const float*)W2v;  // [NI][HID][NN]
            {
                const int h4 = (tid & 15) * 4, e4 = (tid >> 4) * 4;
                char* base = (char*)&sW1[0][0][0];
                #pragma unroll
                for (int s = 0; s < 4; ++s) {
                    f32x4 v[4];
                    #pragma unroll
                    for (int k = 0; k < 4; ++k)
                        v[k] = *(const f32x4*)(W1f + ((size_t)inst * E + s * 64 + e4 + k) * HID + c * BH + h4);
                    const int U = s * 8 + (tid >> 5), sub = (tid >> 4) & 1;
                    #pragma unroll
                    for (int jj = 0; jj < 4; ++jj) {
                        const int row = h4 + jj;
                        bf16x4 w;
                        #pragma unroll
                        for (int k = 0; k < 4; ++k) w[k] = (bf16)v[k][jj];
                        *(bf16x4*)(base + row * 512 + (U ^ (row & 7)) * 16 + sub * 8) = w;
                    }
                }
            }
            {
                const int n4 = (tid & 31) * 4, hq = (tid >> 5) * 4;
                char* base = (char*)&sW2[0][0][0];
                #pragma unroll
                for (int s = 0; s < 2; ++s) {
                    f32x4 v[4];
                    #pragma unroll
                    for (int k = 0; k < 4; ++k)
                        v[k] = *(const f32x4*)(W2f + ((size_t)inst * HID + c * BH + s * 32 + hq + k) * NN + n4);
                    const int U = s * 4 + (tid >> 6), sub = (tid >> 5) & 1;
                    #pragma unroll
                    for (int jj = 0; jj < 4; ++jj) {
                        const int row = n4 + jj;
                        bf16x4 w;
                        #pragma unroll
                        for (int k = 0; k < 4; ++k) w[k] = (bf16)v[k][jj];
                        *(bf16x4*)(base + row * 128 + (U ^ (row & 7)) * 16 + sub * 8) = w;
                    }
                }
            }
        }

        __syncthreads();   // PRET: drains DMA (vmcnt0) + all waves done with other buf
        if (PRET && c + 1 < NCH) issue_dma(c + 1, buf ^ 1);
        const int rb = PRET ? buf : 0;

        // ---- GEMM1 (per ct: 8 b-frag reads, 32 MFMA), fused GELU -> sH ----
        #pragma unroll
        for (int ct = 0; ct < 4; ++ct) {
            f32x4 S[4];
            #pragma unroll
            for (int rt = 0; rt < 4; ++rt) S[rt] = (f32x4){0.f, 0.f, 0.f, 0.f};
            const char* rowp = (const char*)&sW1[rb][ct * 16 + m][0];
            #pragma unroll
            for (int ks = 0; ks < 8; ++ks) {
                const int u = (ks * 4 + q) ^ (m & 7);
                bf16x8 b = *(const bf16x8*)(rowp + u * 16);
                #pragma unroll
                for (int rt = 0; rt < 4; ++rt)
                    S[rt] = MFMA16(aF[rt][ks], b, S[rt]);
            }
            #pragma unroll
            for (int rt = 0; rt < 4; ++rt)
                #pragma unroll
                for (int rr = 0; rr < 4; ++rr)
                    sH[wave * 64 + rt * 16 + q * 4 + rr][ct * 16 + m] =
                        (bf16)fast_gelu(S[rt][rr]);
        }
        asm volatile("s_waitcnt lgkmcnt(0)" ::: "memory");  // own-wave RAW on sH

        // ---- GEMM2: O += gelu(H) @ W2c ----
        #pragma unroll
        for (int k2 = 0; k2 < 2; ++k2) {
            bf16x8 h[4];
            #pragma unroll
            for (int rt = 0; rt < 4; ++rt)
                h[rt] = *(const bf16x8*)&sH[wave * 64 + rt * 16 + m][k2 * 32 + q * 8];
            #pragma unroll
            for (int ct = 0; ct < 8; ++ct) {
                const int u = (k2 * 4 + q) ^ (m & 7);
                bf16x8 b = *(const bf16x8*)((const char*)&sW2[rb][ct * 16 + m][0] + u * 16);
                #pragma unroll
                for (int rt = 0; rt < 4; ++rt)
                    O[rt][ct] = MFMA16(h[rt], b, O[rt][ct]);
            }
        }
    }

    // ---- epilogue: out[b, inst, n] fp32 ----
    #pragma unroll
    for (int rt = 0; rt < 4; ++rt)
        #pragma unroll
        for (int ct = 0; ct < 8; ++ct)
            #pragma unroll
            for (int rr = 0; rr < 4; ++rr) {
                const int b = btile * BM + wave * 64 + rt * 16 + q * 4 + rr;
                const int n = ct * 16 + m;
                out[((size_t)b * NI + inst) * NN + n] = O[rt][ct][rr];
            }
}

extern "C" void kernel_launch(void* const* d_in, const int* in_sizes, int n_in,
                              void* d_out, int out_size, void* d_ws, size_t ws_size,
                              hipStream_t stream)
{
    const int*   a    = (const int*)d_in[0];
    const float* embL = (const float*)d_in[1];
    const float* embR = (const float*)d_in[2];
    const float* lin  = (const float*)d_in[3];   // [NI][E][HID] f32
    const float* une  = (const float*)d_in[4];   // [NI][HID][NN] f32
    float* out = (float*)d_out;

    const size_t w1t_elems = (size_t)NI * HID * E;   // 16.78M bf16
    const size_t w2t_elems = (size_t)NI * NN * HID;  //  8.39M bf16
    const size_t need = (w1t_elems + w2t_elems) * sizeof(bf16);  // ~50.3 MB

    const int nblocks = (BATCH / BM) * NI;  // 512

    if (ws_size >= need) {
        bf16* w1t = (bf16*)d_ws;
        bf16* w2t = w1t + w1t_elems;
        // W1: [NI][E][HID] -> img [NI][HID][E]
        prep_t<<<dim3(E / 64, HID / 128, NI), 256, 0, stream>>>(lin, w1t, E, HID);
        // W2: [NI][HID][NN] -> img [NI][NN][HID]
        prep_t<<<dim3(HID / 64, NN / 128, NI), 256, 0, stream>>>(une, w2t, HID, NN);
        mlp3_fused<true><<<nblocks, 256, 0, stream>>>(
            a, embL, embR, (const void*)w1t, (const void*)w2t, out);
    } else {
        mlp3_fused<false><<<nblocks, 256, 0, stream>>>(
            a, embL, embR, (const void*)lin, (const void*)une, out);
    }
}